// Round 1
// baseline (61.831 us; speedup 1.0000x reference)
//
#include <hip/hip_runtime.h>

// MMDet RoI mask paste: masks [128,1,28,28] f32, boxes [128,4] f32 (xyxy,
// image scale), out [128,800,800] f32. Separable bilinear grid_sample,
// align_corners=false, zeros padding.
//
// One block per (roi, image_row). Threads 0..27 build the y-interpolated
// 28-float row in LDS; threads 0..199 each write 4 pixels as a float4.
// Write-BW-bound: 327.7 MB stores -> ~52us floor at 6.3 TB/s.

#define RR 28        // mask resolution
#define IMG 800      // canvas H = W
#define PX_PER_THREAD 4
#define ROW_THREADS (IMG / PX_PER_THREAD)   // 200

__global__ __launch_bounds__(256) void roi_paste_kernel(
    const float* __restrict__ masks,   // [N,1,28,28]
    const float* __restrict__ boxes,   // [N,4] xyxy
    float* __restrict__ out) {         // [N,800,800]
  const int y = blockIdx.x;            // 0..799
  const int n = blockIdx.y;            // 0..127

  const float x0 = boxes[n * 4 + 0];
  const float y0 = boxes[n * 4 + 1];
  const float x1 = boxes[n * 4 + 2];
  const float y1 = boxes[n * 4 + 3];

  // --- per-row y interpolation into LDS (28 floats) ---
  __shared__ float ry[RR];
  const float py = ((float)y + 0.5f - y0) / (y1 - y0) * (float)RR - 0.5f;
  const float yfl = floorf(py);
  const float wy = py - yfl;
  const int yi = (int)yfl;

  const int t = threadIdx.x;
  if (t < RR) {
    const float* mrow = masks + (size_t)n * RR * RR;
    float a = (yi >= 0 && yi < RR)          ? mrow[yi * RR + t]       : 0.0f;
    float b = (yi + 1 >= 0 && yi + 1 < RR)  ? mrow[(yi + 1) * RR + t] : 0.0f;
    ry[t] = a * (1.0f - wy) + b * wy;
  }
  __syncthreads();

  if (t < ROW_THREADS) {
    const float xscale = (float)RR / (x1 - x0);
    const int xb = t * PX_PER_THREAD;
    float v[PX_PER_THREAD];
#pragma unroll
    for (int k = 0; k < PX_PER_THREAD; ++k) {
      const float px = ((float)(xb + k) + 0.5f - x0) * xscale - 0.5f;
      const float xfl = floorf(px);
      const float wx = px - xfl;
      const int xi = (int)xfl;
      const float a = (xi >= 0 && xi < RR)         ? ry[xi]     : 0.0f;
      const float b = (xi + 1 >= 0 && xi + 1 < RR) ? ry[xi + 1] : 0.0f;
      v[k] = a * (1.0f - wx) + b * wx;
    }
    float4 pack = make_float4(v[0], v[1], v[2], v[3]);
    *reinterpret_cast<float4*>(
        &out[((size_t)n * IMG + y) * IMG + xb]) = pack;
  }
}

extern "C" void kernel_launch(void* const* d_in, const int* in_sizes, int n_in,
                              void* d_out, int out_size, void* d_ws, size_t ws_size,
                              hipStream_t stream) {
  const float* masks = (const float*)d_in[0];
  const float* boxes = (const float*)d_in[1];
  float* out = (float*)d_out;

  dim3 grid(IMG, 128 /* N_ROIS */);
  dim3 block(256);
  roi_paste_kernel<<<grid, block, 0, stream>>>(masks, boxes, out);
}